// Round 1
// baseline (119.584 us; speedup 1.0000x reference)
//
#include <hip/hip_runtime.h>
#include <hip/hip_bf16.h>

// Problem constants (PhraseCompressor): B=4, T=4096, D=2048, P=1024, Lmax=8, c=128
#define BT    16384   // B*T rows
#define DIM   2048    // K
#define NC    256     // 2*c output cols (c_tok | z_tok)
#define CDIM  128

typedef __attribute__((ext_vector_type(8))) short short8;
typedef __attribute__((ext_vector_type(4))) float f32x4;

__device__ __forceinline__ unsigned short f2bf(float f) {
    union { float f; unsigned u; } v; v.f = f;
    return (unsigned short)((v.u + 0x7fffu + ((v.u >> 16) & 1u)) >> 16);  // RNE
}

// ---------------- Kernel 1: pack W_kv|W_z -> bf16 [256][2048] ----------------
__global__ void convert_w(const float* __restrict__ Wkv, const float* __restrict__ Wz,
                          unsigned short* __restrict__ Wb) {
    int i = blockIdx.x * blockDim.x + threadIdx.x;   // 131072 threads, 4 elems each
    int e = i * 4;
    int n = e >> 11;          // row 0..255
    int k = e & 2047;
    const float* src = (n < CDIM) ? (Wkv + (size_t)n * DIM + k)
                                  : (Wz + (size_t)(n - CDIM) * DIM + k);
    float4 f = *(const float4*)src;
    ushort4 o;
    o.x = f2bf(f.x); o.y = f2bf(f.y); o.z = f2bf(f.z); o.w = f2bf(f.w);
    *(ushort4*)(Wb + e) = o;
}

// ---------------- Kernel 2: CZ[16384][256] = h @ Wb^T (bf16 MFMA) ------------
// Tile: BM=64, BN=64, BK=64. 256 threads = 4 waves in 2x2 wave grid.
// LDS: A,B tiles 64 rows x 128 bytes, XOR-swizzled (byte ^= (row&7)<<4).
__global__ __launch_bounds__(256) void gemm_hw(
    const float* __restrict__ H,             // [16384][2048] f32
    const unsigned short* __restrict__ Wb,   // [256][2048] bf16
    float* __restrict__ CZ)                  // [16384][256] f32
{
    __shared__ unsigned char smem[2 * 64 * 128];
    unsigned char* As = smem;
    unsigned char* Bs = smem + 64 * 128;

    const int tid  = threadIdx.x;
    const int bid  = blockIdx.x;
    const int m0   = (bid >> 2) * 64;
    const int n0   = (bid & 3) * 64;

    const int lane = tid & 63;
    const int wave = tid >> 6;
    const int wm   = (wave >> 1) * 32;
    const int wn   = (wave & 1) * 32;

    const int sr = tid >> 4;          // staging row 0..15 (+16*rr)
    const int sc = (tid & 15) * 4;    // staging col elem (x4)

    f32x4 acc[2][2] = {};

    for (int k0 = 0; k0 < DIM; k0 += 64) {
        // ---- stage A (h, f32->bf16) and B (Wb) into swizzled LDS ----
        #pragma unroll
        for (int rr = 0; rr < 4; ++rr) {
            int row = sr + rr * 16;
            float4 f = *(const float4*)(H + (size_t)(m0 + row) * DIM + k0 + sc);
            ushort4 a4;
            a4.x = f2bf(f.x); a4.y = f2bf(f.y); a4.z = f2bf(f.z); a4.w = f2bf(f.w);
            int aoff = row * 128 + sc * 2;
            aoff ^= (row & 7) << 4;
            *(ushort4*)(As + aoff) = a4;

            ushort4 b4 = *(const ushort4*)(Wb + (size_t)(n0 + row) * DIM + k0 + sc);
            int boff = row * 128 + sc * 2;
            boff ^= (row & 7) << 4;
            *(ushort4*)(Bs + boff) = b4;
        }
        __syncthreads();

        // ---- compute: 2 k-subtiles of 32, 2x2 fragments ----
        #pragma unroll
        for (int ks = 0; ks < 2; ++ks) {
            short8 a[2], b[2];
            #pragma unroll
            for (int f = 0; f < 2; ++f) {
                int arow  = wm + f * 16 + (lane & 15);
                int abyte = arow * 128 + ks * 64 + ((lane >> 4) << 4);
                abyte ^= (arow & 7) << 4;
                a[f] = *(const short8*)(As + abyte);

                int brow  = wn + f * 16 + (lane & 15);
                int bbyte = brow * 128 + ks * 64 + ((lane >> 4) << 4);
                bbyte ^= (brow & 7) << 4;
                b[f] = *(const short8*)(Bs + bbyte);
            }
            #pragma unroll
            for (int i = 0; i < 2; ++i)
                #pragma unroll
                for (int j = 0; j < 2; ++j)
                    acc[i][j] = __builtin_amdgcn_mfma_f32_16x16x32_bf16(
                        a[i], b[j], acc[i][j], 0, 0, 0);
        }
        __syncthreads();
    }

    // ---- epilogue: C/D layout col=lane&15, row=(lane>>4)*4+r ----
    #pragma unroll
    for (int i = 0; i < 2; ++i)
        #pragma unroll
        for (int j = 0; j < 2; ++j)
            #pragma unroll
            for (int r = 0; r < 4; ++r) {
                int row = m0 + wm + i * 16 + (lane >> 4) * 4 + r;
                int col = n0 + wn + j * 16 + (lane & 15);
                CZ[(size_t)row * NC + col] = acc[i][j][r];
            }
}

// ---------------- Kernel 3: gather + masked softmax + weighted reduce --------
// One block handles 2 phrases; thread = (phrase-half, channel).
__global__ __launch_bounds__(256) void finalize(
    const float* __restrict__ CZ,       // [16384][256]
    const int*   __restrict__ mask,     // [4096][8]
    const int*   __restrict__ idx,      // [4096][8]
    const float* __restrict__ Bpos,     // [8][128]
    float*       __restrict__ out)      // [4096][128]
{
    int t  = threadIdx.x;
    int ch = t & 127;
    int q  = blockIdx.x * 2 + (t >> 7);   // linear phrase 0..4095
    int b  = q >> 10;                     // /P (P=1024)

    int rows[8];
    unsigned mbits = 0;
    #pragma unroll
    for (int l = 0; l < 8; ++l) {
        int m   = mask[q * 8 + l];
        int tok = idx[q * 8 + l];
        rows[l] = b * 4096 + tok;
        if (m) mbits |= 1u << l;
    }

    float z[8];
    float mx = -1e30f;
    #pragma unroll
    for (int l = 0; l < 8; ++l) {
        if (mbits & (1u << l)) {
            z[l] = CZ[(size_t)rows[l] * NC + CDIM + ch] + Bpos[l * CDIM + ch];
            mx = fmaxf(mx, z[l]);
        } else {
            z[l] = -1e30f;
        }
    }

    float num = 0.f, den = 0.f;
    #pragma unroll
    for (int l = 0; l < 8; ++l) {
        if (mbits & (1u << l)) {
            float w = __expf(z[l] - mx);
            den += w;
            num += w * CZ[(size_t)rows[l] * NC + ch];
        }
    }
    out[(size_t)q * CDIM + ch] = mbits ? (num / den) : 0.f;
}

extern "C" void kernel_launch(void* const* d_in, const int* in_sizes, int n_in,
                              void* d_out, int out_size, void* d_ws, size_t ws_size,
                              hipStream_t stream) {
    const float* h    = (const float*)d_in[0];
    const int*   mask = (const int*)d_in[1];
    const int*   idx  = (const int*)d_in[2];
    const float* Wkv  = (const float*)d_in[3];
    const float* Wz   = (const float*)d_in[4];
    const float* Bpos = (const float*)d_in[5];
    float* out = (float*)d_out;

    unsigned short* Wb = (unsigned short*)d_ws;                    // 256*2048*2 = 1 MB
    float* CZ = (float*)((char*)d_ws + 2 * 1024 * 1024);           // 16384*256*4 = 16.8 MB

    convert_w<<<512, 256, 0, stream>>>(Wkv, Wz, Wb);
    gemm_hw<<<1024, 256, 0, stream>>>(h, Wb, CZ);
    finalize<<<2048, 256, 0, stream>>>(CZ, mask, idx, Bpos, out);
}

// Round 2
// 61.806 us; speedup vs baseline: 1.9348x; 1.9348x over previous
//
#include <hip/hip_runtime.h>
#include <hip/hip_bf16.h>

// PhraseCompressor: B=4, T=4096, D=2048, P=1024, Lmax=8, c=128
#define DIM   2048
#define NC    256
#define CDIM  128

typedef __attribute__((ext_vector_type(8))) short short8;
typedef __attribute__((ext_vector_type(4))) float f32x4;

static __device__ __forceinline__ unsigned short f2bf(float f) {
    union { float f; unsigned u; } v; v.f = f;
    return (unsigned short)((v.u + 0x7fffu + ((v.u >> 16) & 1u)) >> 16);  // RNE
}

// ---------- Kernel 1: pack W_kv|W_z into fragment-major bf16 Wp[f][s][lane][8] ----
// f = n-fragment 0..15 (cols f*16..f*16+15), s = k-subtile 0..63 (k = s*32..s*32+31)
// Wp element: Wp[((f*64+s)*64+l)*8+e] = W[f*16+(l&15)][s*32+(l>>4)*8+e]
__global__ __launch_bounds__(256) void convert_w(const float* __restrict__ Wkv,
                                                 const float* __restrict__ Wz,
                                                 unsigned short* __restrict__ Wp) {
    int tid = blockIdx.x * 256 + threadIdx.x;      // 65536 threads
    int l = tid & 63;
    int s = (tid >> 6) & 63;
    int f = tid >> 12;
    int n = f * 16 + (l & 15);
    int k = s * 32 + ((l >> 4) << 3);
    const float* src = (n < CDIM) ? (Wkv + (size_t)n * DIM + k)
                                  : (Wz + (size_t)(n - CDIM) * DIM + k);
    float4 f0 = *(const float4*)src;
    float4 f1 = *(const float4*)(src + 4);
    short8 o;
    o[0] = (short)f2bf(f0.x); o[1] = (short)f2bf(f0.y);
    o[2] = (short)f2bf(f0.z); o[3] = (short)f2bf(f0.w);
    o[4] = (short)f2bf(f1.x); o[5] = (short)f2bf(f1.y);
    o[6] = (short)f2bf(f1.z); o[7] = (short)f2bf(f1.w);
    *(short8*)(Wp + (size_t)tid * 8) = o;
}

// ---------- Kernel 2: CZ[16384][256] = h @ W^T, BM=64 BN=256 BK=64 ----------
// 512 threads = 8 waves in 2(m) x 4(n); per wave 32x64 -> acc[2][4].
// LDS: A only, 64 rows x 128 B, double-buffered (16 KB), XOR-swizzled.
// B fragments read directly from packed Wp (L2-resident, coalesced 1KB/wave).
__global__ __launch_bounds__(512) void gemm_hw(
    const float* __restrict__ H,
    const unsigned short* __restrict__ Wp,
    float* __restrict__ CZ)
{
    __shared__ unsigned char As[2 * 64 * 128];

    const int tid  = threadIdx.x;
    const int lane = tid & 63;
    const int wave = tid >> 6;
    const int wm   = (wave >> 2) * 32;    // 0 / 32
    const int wn   = (wave & 3) * 64;     // 0 / 64 / 128 / 192
    const int m0   = blockIdx.x * 64;

    // staging: thread -> 8 consecutive floats of one row
    const int srow = tid >> 3;            // 0..63
    const int scol = (tid & 7) * 8;       // 0..56
    const float* gA = H + (size_t)(m0 + srow) * DIM + scol;
    int soff = srow * 128 + scol * 2;
    soff ^= (srow & 7) << 4;

    // A-fragment read bases (swizzle applied per-ks inside compute)
    int arowbase[2], aswz[2];
    #pragma unroll
    for (int i = 0; i < 2; ++i) {
        int row = wm + i * 16 + (lane & 15);
        arowbase[i] = row * 128 + ((lane >> 4) << 4);
        aswz[i]     = (row & 7) << 4;
    }

    f32x4 acc[2][4] = {};

    float4 pa0, pb0, pa1, pb1;

#define LOADSTAGE(pa, pb, K0) { \
    pa = *(const float4*)(gA + (K0)); \
    pb = *(const float4*)(gA + (K0) + 4); }

#define WRITESTAGE(BUFB, pa, pb) { \
    short8 w_; \
    w_[0] = (short)f2bf(pa.x); w_[1] = (short)f2bf(pa.y); \
    w_[2] = (short)f2bf(pa.z); w_[3] = (short)f2bf(pa.w); \
    w_[4] = (short)f2bf(pb.x); w_[5] = (short)f2bf(pb.y); \
    w_[6] = (short)f2bf(pb.z); w_[7] = (short)f2bf(pb.w); \
    *(short8*)(As + (BUFB) + soff) = w_; }

#define COMPUTE(BUFB, K0) { \
    _Pragma("unroll") \
    for (int ks = 0; ks < 2; ++ks) { \
        int s_ = ((K0) >> 5) + ks; \
        short8 b_[4], a_[2]; \
        _Pragma("unroll") \
        for (int j = 0; j < 4; ++j) \
            b_[j] = *(const short8*)(Wp + ((size_t)(((wn >> 4) + j) * 64 + s_) * 64 + lane) * 8); \
        _Pragma("unroll") \
        for (int i = 0; i < 2; ++i) { \
            int off_ = (arowbase[i] + ks * 64) ^ aswz[i]; \
            a_[i] = *(const short8*)(As + (BUFB) + off_); \
        } \
        _Pragma("unroll") \
        for (int i = 0; i < 2; ++i) \
            _Pragma("unroll") \
            for (int j = 0; j < 4; ++j) \
                acc[i][j] = __builtin_amdgcn_mfma_f32_16x16x32_bf16(a_[i], b_[j], acc[i][j], 0, 0, 0); \
    } }

    // prologue: prefetch k=0 and k=64, commit k=0 to buf0
    LOADSTAGE(pa0, pb0, 0);
    LOADSTAGE(pa1, pb1, 64);
    WRITESTAGE(0, pa0, pb0);
    __syncthreads();

    // 32 K-steps, unrolled x2 for static reg parity (prefetch depth 2)
    for (int it = 0; it < 16; ++it) {
        const int k0 = it * 128;
        if (it < 15) LOADSTAGE(pa0, pb0, k0 + 128);
        COMPUTE(0, k0);
        WRITESTAGE(8192, pa1, pb1);            // k0+64 always < 2048
        __syncthreads();

        if (it < 15) LOADSTAGE(pa1, pb1, k0 + 192);
        COMPUTE(8192, k0 + 64);
        if (it < 15) WRITESTAGE(0, pa0, pb0);
        __syncthreads();
    }

    // epilogue: C/D layout col=lane&15, row=(lane>>4)*4+r
    #pragma unroll
    for (int i = 0; i < 2; ++i)
        #pragma unroll
        for (int j = 0; j < 4; ++j)
            #pragma unroll
            for (int r = 0; r < 4; ++r) {
                int row = m0 + wm + i * 16 + (lane >> 4) * 4 + r;
                int col = wn + j * 16 + (lane & 15);
                CZ[(size_t)row * NC + col] = acc[i][j][r];
            }
#undef LOADSTAGE
#undef WRITESTAGE
#undef COMPUTE
}

// ---------- Kernel 3: gather + masked softmax + weighted reduce --------------
__global__ __launch_bounds__(256) void finalize(
    const float* __restrict__ CZ,
    const int*   __restrict__ mask,
    const int*   __restrict__ idx,
    const float* __restrict__ Bpos,
    float*       __restrict__ out)
{
    int t  = threadIdx.x;
    int ch = t & 127;
    int q  = blockIdx.x * 2 + (t >> 7);   // linear phrase 0..4095
    int b  = q >> 10;

    int rows[8];
    unsigned mbits = 0;
    #pragma unroll
    for (int l = 0; l < 8; ++l) {
        int m   = mask[q * 8 + l];
        int tok = idx[q * 8 + l];
        rows[l] = b * 4096 + tok;
        if (m) mbits |= 1u << l;
    }

    float z[8];
    float mx = -1e30f;
    #pragma unroll
    for (int l = 0; l < 8; ++l) {
        if (mbits & (1u << l)) {
            z[l] = CZ[(size_t)rows[l] * NC + CDIM + ch] + Bpos[l * CDIM + ch];
            mx = fmaxf(mx, z[l]);
        } else {
            z[l] = -1e30f;
        }
    }

    float num = 0.f, den = 0.f;
    #pragma unroll
    for (int l = 0; l < 8; ++l) {
        if (mbits & (1u << l)) {
            float w = __expf(z[l] - mx);
            den += w;
            num += w * CZ[(size_t)rows[l] * NC + ch];
        }
    }
    out[(size_t)q * CDIM + ch] = mbits ? (num / den) : 0.f;
}

extern "C" void kernel_launch(void* const* d_in, const int* in_sizes, int n_in,
                              void* d_out, int out_size, void* d_ws, size_t ws_size,
                              hipStream_t stream) {
    const float* h    = (const float*)d_in[0];
    const int*   mask = (const int*)d_in[1];
    const int*   idx  = (const int*)d_in[2];
    const float* Wkv  = (const float*)d_in[3];
    const float* Wz   = (const float*)d_in[4];
    const float* Bpos = (const float*)d_in[5];
    float* out = (float*)d_out;

    unsigned short* Wp = (unsigned short*)d_ws;                 // 1 MB packed weights
    float* CZ = (float*)((char*)d_ws + 2 * 1024 * 1024);        // 16.8 MB

    convert_w<<<256, 256, 0, stream>>>(Wkv, Wz, Wp);
    gemm_hw<<<256, 512, 0, stream>>>(h, Wp, CZ);
    finalize<<<2048, 256, 0, stream>>>(CZ, mask, idx, Bpos, out);
}

// Round 3
// 56.998 us; speedup vs baseline: 2.0980x; 1.0843x over previous
//
#include <hip/hip_runtime.h>
#include <hip/hip_bf16.h>

// PhraseCompressor: B=4, T=4096, D=2048, P=1024, Lmax=8, c=128
#define DIM   2048
#define NC    256
#define CDIM  128

typedef __attribute__((ext_vector_type(8))) short short8;
typedef __attribute__((ext_vector_type(4))) float f32x4;

static __device__ __forceinline__ unsigned short f2bf(float f) {
    union { float f; unsigned u; } v; v.f = f;
    return (unsigned short)((v.u + 0x7fffu + ((v.u >> 16) & 1u)) >> 16);  // RNE
}

// ---------- Kernel 1: pack W_kv|W_z into fragment-major bf16 Wp ----------
// frag f 0..15 (cols f*16..f*16+15), k-subtile s 0..63 (k = s*32+..)
// Wp[((f*64+s)*64+l)*8+e] = W[f*16+(l&15)][s*32+(l>>4)*8+e]
__global__ __launch_bounds__(256) void convert_w(const float* __restrict__ Wkv,
                                                 const float* __restrict__ Wz,
                                                 unsigned short* __restrict__ Wp) {
    int tid = blockIdx.x * 256 + threadIdx.x;      // 65536 threads
    int l = tid & 63;
    int s = (tid >> 6) & 63;
    int f = tid >> 12;
    int n = f * 16 + (l & 15);
    int k = s * 32 + ((l >> 4) << 3);
    const float* src = (n < CDIM) ? (Wkv + (size_t)n * DIM + k)
                                  : (Wz + (size_t)(n - CDIM) * DIM + k);
    float4 f0 = *(const float4*)src;
    float4 f1 = *(const float4*)(src + 4);
    short8 o;
    o[0] = (short)f2bf(f0.x); o[1] = (short)f2bf(f0.y);
    o[2] = (short)f2bf(f0.z); o[3] = (short)f2bf(f0.w);
    o[4] = (short)f2bf(f1.x); o[5] = (short)f2bf(f1.y);
    o[6] = (short)f2bf(f1.z); o[7] = (short)f2bf(f1.w);
    *(short8*)(Wp + (size_t)tid * 8) = o;
}

// ---------- Kernel 2: CZ[16384][256] = h @ W^T, BM=32 BN=256 BK=64 ----------
// 256 threads = 4 waves, wave w covers rows 0..31 x cols w*64..w*64+63 -> acc[2][4].
// Grid 512 -> 2 blocks/CU (independent barrier domains).
// A: 32x64 bf16 LDS, double-buffered (8 KB), XOR swizzle, reg-staged depth-2.
// B: fragment-major Wp, register-prefetched one K-step ahead (no LDS).
__global__ __launch_bounds__(256) void gemm_hw(
    const float* __restrict__ H,
    const unsigned short* __restrict__ Wp,
    float* __restrict__ CZ)
{
    __shared__ unsigned char As[2 * 32 * 128];

    const int tid  = threadIdx.x;
    const int lane = tid & 63;
    const int wave = tid >> 6;
    const int wn   = wave * 64;
    const int m0   = blockIdx.x * 32;

    // A staging: thread loads 8 consecutive floats of one row
    const int srow = tid >> 3;            // 0..31
    const int scol = (tid & 7) * 8;       // 0..56
    const float* gA = H + (size_t)(m0 + srow) * DIM + scol;
    int soff = (srow * 128 + scol * 2) ^ ((srow & 7) << 4);

    // A fragment read offsets
    int aoff[2];
    #pragma unroll
    for (int i = 0; i < 2; ++i) {
        int row = i * 16 + (lane & 15);
        aoff[i] = (row * 128 + ((lane >> 4) << 4)) ^ ((row & 7) << 4);
    }

    // B fragment base: addr(j,s) = wpb + j*32768 + s*512  (elements)
    const unsigned short* wpb = Wp + (size_t)(wn >> 4) * 32768 + lane * 8;

    f32x4 acc[2][4] = {};
    float4 pa0, pb0, pa1, pb1;
    short8 b0[2][4], b1[2][4];

#define LOADA(pa, pb, K0) { \
    pa = *(const float4*)(gA + (K0)); \
    pb = *(const float4*)(gA + (K0) + 4); }

#define LOADB(B, K0) { \
    _Pragma("unroll") \
    for (int ks = 0; ks < 2; ++ks) \
        _Pragma("unroll") \
        for (int j = 0; j < 4; ++j) \
            B[ks][j] = *(const short8*)(wpb + j * 32768 + (((K0) >> 5) + ks) * 512); }

#define WRITES(BUFB, pa, pb) { \
    short8 w_; \
    w_[0] = (short)f2bf(pa.x); w_[1] = (short)f2bf(pa.y); \
    w_[2] = (short)f2bf(pa.z); w_[3] = (short)f2bf(pa.w); \
    w_[4] = (short)f2bf(pb.x); w_[5] = (short)f2bf(pb.y); \
    w_[6] = (short)f2bf(pb.z); w_[7] = (short)f2bf(pb.w); \
    *(short8*)(As + (BUFB) + soff) = w_; }

#define COMPUTE(BUFB, B) { \
    _Pragma("unroll") \
    for (int ks = 0; ks < 2; ++ks) { \
        short8 a_[2]; \
        _Pragma("unroll") \
        for (int i = 0; i < 2; ++i) \
            a_[i] = *(const short8*)(As + (BUFB) + (aoff[i] + ks * 64)); \
        _Pragma("unroll") \
        for (int i = 0; i < 2; ++i) \
            _Pragma("unroll") \
            for (int j = 0; j < 4; ++j) \
                acc[i][j] = __builtin_amdgcn_mfma_f32_16x16x32_bf16(a_[i], B[ks][j], acc[i][j], 0, 0, 0); \
    } }

    // NOTE: aoff[i] + ks*64 then XOR-swizzle — swizzle bits are in byte 4..6 of
    // offset; ks*64 touches bit 6. aoff already includes swizzle, and ks*64 is
    // added after XOR; since swizzle uses bit 4 only ((row&7)<<4 has bits 4..6)
    // addition could carry into swizzled bits. Avoid: apply ks before XOR.
#undef COMPUTE
#define COMPUTE(BUFB, B) { \
    _Pragma("unroll") \
    for (int ks = 0; ks < 2; ++ks) { \
        short8 a_[2]; \
        _Pragma("unroll") \
        for (int i = 0; i < 2; ++i) { \
            int row_ = i * 16 + (lane & 15); \
            int off_ = (row_ * 128 + ks * 64 + ((lane >> 4) << 4)) ^ ((row_ & 7) << 4); \
            a_[i] = *(const short8*)(As + (BUFB) + off_); \
        } \
        _Pragma("unroll") \
        for (int i = 0; i < 2; ++i) \
            _Pragma("unroll") \
            for (int j = 0; j < 4; ++j) \
                acc[i][j] = __builtin_amdgcn_mfma_f32_16x16x32_bf16(a_[i], B[ks][j], acc[i][j], 0, 0, 0); \
    } }

    // ---- prologue ----
    LOADA(pa0, pb0, 0);
    LOADB(b0, 0);
    WRITES(0, pa0, pb0);
    LOADA(pa1, pb1, 64);
    __syncthreads();

    // ---- 32 K-steps, unrolled x2 ----
    for (int it = 0; it < 32; it += 2) {
        // even step: buf0, b0
        if (it + 1 < 32) LOADB(b1, (it + 1) * 64);
        WRITES(4096, pa1, pb1);                       // stage A step it+1
        if (it + 2 < 32) LOADA(pa0, pb0, (it + 2) * 64);
        COMPUTE(0, b0);
        __syncthreads();

        // odd step: buf1, b1
        if (it + 2 < 32) LOADB(b0, (it + 2) * 64);
        if (it + 2 < 32) WRITES(0, pa0, pb0);
        if (it + 3 < 32) LOADA(pa1, pb1, (it + 3) * 64);
        COMPUTE(4096, b1);
        __syncthreads();
    }

    // ---- epilogue: C/D layout col=lane&15, row=(lane>>4)*4+r ----
    #pragma unroll
    for (int i = 0; i < 2; ++i)
        #pragma unroll
        for (int j = 0; j < 4; ++j)
            #pragma unroll
            for (int r = 0; r < 4; ++r) {
                int row = m0 + i * 16 + (lane >> 4) * 4 + r;
                int col = wn + j * 16 + (lane & 15);
                CZ[(size_t)row * NC + col] = acc[i][j][r];
            }
#undef LOADA
#undef LOADB
#undef WRITES
#undef COMPUTE
}

// ---------- Kernel 3: gather + masked softmax + weighted reduce --------------
__global__ __launch_bounds__(256) void finalize(
    const float* __restrict__ CZ,
    const int*   __restrict__ mask,
    const int*   __restrict__ idx,
    const float* __restrict__ Bpos,
    float*       __restrict__ out)
{
    int t  = threadIdx.x;
    int ch = t & 127;
    int q  = blockIdx.x * 2 + (t >> 7);   // linear phrase 0..4095
    int b  = q >> 10;

    int rows[8];
    unsigned mbits = 0;
    #pragma unroll
    for (int l = 0; l < 8; ++l) {
        int m   = mask[q * 8 + l];
        int tok = idx[q * 8 + l];
        rows[l] = b * 4096 + tok;
        if (m) mbits |= 1u << l;
    }

    float z[8];
    float mx = -1e30f;
    #pragma unroll
    for (int l = 0; l < 8; ++l) {
        if (mbits & (1u << l)) {
            z[l] = CZ[(size_t)rows[l] * NC + CDIM + ch] + Bpos[l * CDIM + ch];
            mx = fmaxf(mx, z[l]);
        } else {
            z[l] = -1e30f;
        }
    }

    float num = 0.f, den = 0.f;
    #pragma unroll
    for (int l = 0; l < 8; ++l) {
        if (mbits & (1u << l)) {
            float w = __expf(z[l] - mx);
            den += w;
            num += w * CZ[(size_t)rows[l] * NC + ch];
        }
    }
    out[(size_t)q * CDIM + ch] = mbits ? (num / den) : 0.f;
}

extern "C" void kernel_launch(void* const* d_in, const int* in_sizes, int n_in,
                              void* d_out, int out_size, void* d_ws, size_t ws_size,
                              hipStream_t stream) {
    const float* h    = (const float*)d_in[0];
    const int*   mask = (const int*)d_in[1];
    const int*   idx  = (const int*)d_in[2];
    const float* Wkv  = (const float*)d_in[3];
    const float* Wz   = (const float*)d_in[4];
    const float* Bpos = (const float*)d_in[5];
    float* out = (float*)d_out;

    unsigned short* Wp = (unsigned short*)d_ws;                 // 1 MB packed weights
    float* CZ = (float*)((char*)d_ws + 2 * 1024 * 1024);        // 16.8 MB

    convert_w<<<256, 256, 0, stream>>>(Wkv, Wz, Wp);
    gemm_hw<<<512, 256, 0, stream>>>(h, Wp, CZ);
    finalize<<<2048, 256, 0, stream>>>(CZ, mask, idx, Bpos, out);
}

// Round 4
// 47.238 us; speedup vs baseline: 2.5315x; 1.2066x over previous
//
#include <hip/hip_runtime.h>
#include <hip/hip_bf16.h>

// PhraseCompressor: B=4, T=4096, D=2048, P=1024, Lmax=8, c=128
#define DIM   2048
#define NC    256
#define CDIM  128
#define HALFCZ (16384u * 256u)   // elems per split-K partial

typedef __attribute__((ext_vector_type(8))) short short8;
typedef __attribute__((ext_vector_type(4))) float f32x4;

static __device__ __forceinline__ unsigned short f2bf(float f) {
    union { float f; unsigned u; } v; v.f = f;
    return (unsigned short)((v.u + 0x7fffu + ((v.u >> 16) & 1u)) >> 16);  // RNE
}

// pack 8 f32 -> 8 bf16 (compiler emits v_cvt_pk_bf16_f32 pairs)
static __device__ __forceinline__ short8 cvt8(float4 a, float4 b) {
    union { __hip_bfloat162 h2[4]; short8 s; } u;
    u.h2[0] = __float22bfloat162_rn(float2{a.x, a.y});
    u.h2[1] = __float22bfloat162_rn(float2{a.z, a.w});
    u.h2[2] = __float22bfloat162_rn(float2{b.x, b.y});
    u.h2[3] = __float22bfloat162_rn(float2{b.z, b.w});
    return u.s;
}

// ---------- Kernel 1: pack W_kv|W_z into fragment-major bf16 Wp ----------
// frag f 0..15 (cols f*16..), k-subtile s 0..63 (k = s*32..)
// Wp[((f*64+s)*64+l)*8+e] = W[f*16+(l&15)][s*32+(l>>4)*8+e]
__global__ __launch_bounds__(256) void convert_w(const float* __restrict__ Wkv,
                                                 const float* __restrict__ Wz,
                                                 unsigned short* __restrict__ Wp) {
    int tid = blockIdx.x * 256 + threadIdx.x;      // 65536 threads
    int l = tid & 63;
    int s = (tid >> 6) & 63;
    int f = tid >> 12;
    int n = f * 16 + (l & 15);
    int k = s * 32 + ((l >> 4) << 3);
    const float* src = (n < CDIM) ? (Wkv + (size_t)n * DIM + k)
                                  : (Wz + (size_t)(n - CDIM) * DIM + k);
    float4 f0 = *(const float4*)src;
    float4 f1 = *(const float4*)(src + 4);
    *(short8*)(Wp + (size_t)tid * 8) = cvt8(f0, f1);
}

// ---------- Kernel 2: CZp[ks][16384][256] = h @ W^T (K-slice) ----------
// BM=64, BN=256, BK=64, split-K=2 (K=1024/block). 256 thr = 4 waves,
// wave w: all 64 rows x cols w*64..w*64+63 -> acc[4][4] (64 regs).
// Grid 512 -> 2 blocks/CU, two independent 4-wave barrier domains.
// A: 64x64 bf16 LDS dbuf (16 KB), XOR swizzle, reg-staged depth-2.
// B: fragment-major Wp from L2, reg-prefetched one K-step ahead.
__global__ __launch_bounds__(256) void gemm_hw(
    const float* __restrict__ H,
    const unsigned short* __restrict__ Wp,
    float* __restrict__ CZp)
{
    __shared__ unsigned char As[2 * 64 * 128];

    const int tid    = threadIdx.x;
    const int lane   = tid & 63;
    const int wave   = tid >> 6;        // 0..3
    const int wn     = wave * 64;
    const int bid    = blockIdx.x;
    const int kslice = bid & 1;
    const int m0     = (bid >> 1) * 64;

    float* CZout = CZp + (size_t)kslice * HALFCZ;

    // A staging: thread -> 16 consecutive floats of one row
    const int srow  = tid >> 2;          // 0..63
    const int scolf = (tid & 3) * 16;    // 0/16/32/48
    const float* gA = H + (size_t)(m0 + srow) * DIM + kslice * 1024 + scolf;
    const int swz   = (srow & 7) << 4;
    const int soff0 = (srow * 128 + scolf * 2) ^ swz;
    const int soff1 = (srow * 128 + scolf * 2 + 16) ^ swz;

    // B fragment base: frag index = wave*4 + j ; addr = wpb + j*32768 + s*512
    const unsigned short* wpb = Wp + (size_t)(wave * 4) * 32768 + lane * 8;

    f32x4 acc[4][4] = {};
    float4 p0[4], p1[4];
    short8 b0[2][4], b1[2][4];

#define LOADA(P, KT) { \
    _Pragma("unroll") \
    for (int q = 0; q < 4; ++q) P[q] = *(const float4*)(gA + (KT) * 64 + q * 4); }

#define LOADB(B, KT) { \
    _Pragma("unroll") \
    for (int ks = 0; ks < 2; ++ks) \
        _Pragma("unroll") \
        for (int j = 0; j < 4; ++j) \
            B[ks][j] = *(const short8*)(wpb + (size_t)j * 32768 + ((kslice << 5) + (KT) * 2 + ks) * 512); }

#define WRITES(BUFB, P) { \
    short8 lo_ = cvt8(P[0], P[1]); \
    short8 hi_ = cvt8(P[2], P[3]); \
    *(short8*)(As + (BUFB) + soff0) = lo_; \
    *(short8*)(As + (BUFB) + soff1) = hi_; }

#define COMPUTE(BUFB, B) { \
    _Pragma("unroll") \
    for (int ks = 0; ks < 2; ++ks) { \
        short8 a_[4]; \
        _Pragma("unroll") \
        for (int i = 0; i < 4; ++i) { \
            int row_ = i * 16 + (lane & 15); \
            int off_ = (row_ * 128 + ks * 64 + ((lane >> 4) << 4)) ^ ((row_ & 7) << 4); \
            a_[i] = *(const short8*)(As + (BUFB) + off_); \
        } \
        _Pragma("unroll") \
        for (int i = 0; i < 4; ++i) \
            _Pragma("unroll") \
            for (int j = 0; j < 4; ++j) \
                acc[i][j] = __builtin_amdgcn_mfma_f32_16x16x32_bf16(a_[i], B[ks][j], acc[i][j], 0, 0, 0); \
    } }

    // ---- prologue: stage step0, prefetch step1 ----
    LOADA(p0, 0);
    LOADB(b0, 0);
    WRITES(0, p0);
    LOADA(p1, 1);
    __syncthreads();

    // ---- 16 K-steps (K=1024), unrolled x2, 1 barrier per step ----
    for (int it = 0; it < 16; it += 2) {
        LOADB(b1, it + 1);
        WRITES(8192, p1);                       // stage it+1 into buf1
        if (it + 2 < 16) LOADA(p0, it + 2);
        COMPUTE(0, b0);
        __syncthreads();

        if (it + 2 < 16) { LOADB(b0, it + 2); WRITES(0, p0); }
        if (it + 3 < 16) LOADA(p1, it + 3);
        COMPUTE(8192, b1);
        __syncthreads();
    }

    // ---- epilogue: C/D layout col=lane&15, row=(lane>>4)*4+r ----
    #pragma unroll
    for (int i = 0; i < 4; ++i)
        #pragma unroll
        for (int j = 0; j < 4; ++j)
            #pragma unroll
            for (int r = 0; r < 4; ++r) {
                int row = m0 + i * 16 + (lane >> 4) * 4 + r;
                int col = wn + j * 16 + (lane & 15);
                CZout[(size_t)row * NC + col] = acc[i][j][r];
            }
#undef LOADA
#undef LOADB
#undef WRITES
#undef COMPUTE
}

// ---------- Kernel 3: sum split-K + gather + masked softmax + reduce ----------
__global__ __launch_bounds__(256) void finalize(
    const float* __restrict__ CZp,
    const int*   __restrict__ mask,
    const int*   __restrict__ idx,
    const float* __restrict__ Bpos,
    float*       __restrict__ out)
{
    const float* CZ0 = CZp;
    const float* CZ1 = CZp + HALFCZ;

    int t  = threadIdx.x;
    int ch = t & 127;
    int q  = blockIdx.x * 2 + (t >> 7);   // linear phrase 0..4095
    int b  = q >> 10;

    int rows[8];
    unsigned mbits = 0;
    #pragma unroll
    for (int l = 0; l < 8; ++l) {
        int m   = mask[q * 8 + l];
        int tok = idx[q * 8 + l];
        rows[l] = b * 4096 + tok;
        if (m) mbits |= 1u << l;
    }

    float z[8], c[8];
    float mx = -1e30f;
    #pragma unroll
    for (int l = 0; l < 8; ++l) {
        if (mbits & (1u << l)) {
            size_t base = (size_t)rows[l] * NC;
            z[l] = CZ0[base + CDIM + ch] + CZ1[base + CDIM + ch] + Bpos[l * CDIM + ch];
            c[l] = CZ0[base + ch] + CZ1[base + ch];
            mx = fmaxf(mx, z[l]);
        } else {
            z[l] = -1e30f; c[l] = 0.f;
        }
    }

    float num = 0.f, den = 0.f;
    #pragma unroll
    for (int l = 0; l < 8; ++l) {
        if (mbits & (1u << l)) {
            float w = __expf(z[l] - mx);
            den += w;
            num += w * c[l];
        }
    }
    out[(size_t)q * CDIM + ch] = mbits ? (num / den) : 0.f;
}

extern "C" void kernel_launch(void* const* d_in, const int* in_sizes, int n_in,
                              void* d_out, int out_size, void* d_ws, size_t ws_size,
                              hipStream_t stream) {
    const float* h    = (const float*)d_in[0];
    const int*   mask = (const int*)d_in[1];
    const int*   idx  = (const int*)d_in[2];
    const float* Wkv  = (const float*)d_in[3];
    const float* Wz   = (const float*)d_in[4];
    const float* Bpos = (const float*)d_in[5];
    float* out = (float*)d_out;

    unsigned short* Wp = (unsigned short*)d_ws;                 // 1 MB packed weights
    float* CZp = (float*)((char*)d_ws + 2 * 1024 * 1024);       // 2 x 16.8 MB partials

    convert_w<<<256, 256, 0, stream>>>(Wkv, Wz, Wp);
    gemm_hw<<<512, 256, 0, stream>>>(h, Wp, CZp);
    finalize<<<2048, 256, 0, stream>>>(CZp, mask, idx, Bpos, out);
}

// Round 8
// 43.913 us; speedup vs baseline: 2.7232x; 1.0757x over previous
//
#include <hip/hip_runtime.h>
#include <hip/hip_bf16.h>

// PhraseCompressor: B=4, T=4096, D=2048, P=1024, Lmax=8, c=128
#define DIM   2048
#define NC    256
#define CDIM  128
#define HALFCZ (16384u * 256u)   // elems per split-K partial

typedef __attribute__((ext_vector_type(8))) short short8;
typedef __attribute__((ext_vector_type(4))) float f32x4;

static __device__ __forceinline__ unsigned short f2bf(float f) {
    union { float f; unsigned u; } v; v.f = f;
    return (unsigned short)((v.u + 0x7fffu + ((v.u >> 16) & 1u)) >> 16);  // RNE
}
static __device__ __forceinline__ float bf2f(unsigned short u) {
    union { unsigned u; float f; } v; v.u = ((unsigned)u) << 16; return v.f;
}

// pack 8 f32 -> 8 bf16 (compiler emits v_cvt_pk_bf16_f32 pairs)
static __device__ __forceinline__ short8 cvt8(float4 a, float4 b) {
    union { __hip_bfloat162 h2[4]; short8 s; } u;
    u.h2[0] = __float22bfloat162_rn(float2{a.x, a.y});
    u.h2[1] = __float22bfloat162_rn(float2{a.z, a.w});
    u.h2[2] = __float22bfloat162_rn(float2{b.x, b.y});
    u.h2[3] = __float22bfloat162_rn(float2{b.z, b.w});
    return u.s;
}

// lgkm-only barrier: keep global (vmcnt) prefetch loads in flight across it.
// Safe because LDS contents only depend on ds_write (lgkm); in-flight global
// loads land in registers whose consumers get compiler-inserted vmcnt waits.
#define BARRIER() { asm volatile("s_waitcnt lgkmcnt(0)" ::: "memory"); \
                    __builtin_amdgcn_s_barrier(); }

// ---------- Kernel 1: pack W_kv|W_z into fragment-major bf16 Wp ----------
// frag f 0..15 (cols f*16..), k-subtile s 0..63 (k = s*32..)
// Wp[((f*64+s)*64+l)*8+e] = W[f*16+(l&15)][s*32+(l>>4)*8+e]
__global__ __launch_bounds__(256) void convert_w(const float* __restrict__ Wkv,
                                                 const float* __restrict__ Wz,
                                                 unsigned short* __restrict__ Wp) {
    int tid = blockIdx.x * 256 + threadIdx.x;      // 65536 threads
    int l = tid & 63;
    int s = (tid >> 6) & 63;
    int f = tid >> 12;
    int n = f * 16 + (l & 15);
    int k = s * 32 + ((l >> 4) << 3);
    const float* src = (n < CDIM) ? (Wkv + (size_t)n * DIM + k)
                                  : (Wz + (size_t)(n - CDIM) * DIM + k);
    float4 f0 = *(const float4*)src;
    float4 f1 = *(const float4*)(src + 4);
    *(short8*)(Wp + (size_t)tid * 8) = cvt8(f0, f1);
}

// ---------- Kernel 2: CZp[ks][16384][256] = h @ W^T (K-slice, bf16 out) ------
// BM=64, BN=256, split-K=2. 256 thr = 4 waves; wave w: 64 rows x cols w*64..+63
// -> acc[4][4]. Grid 512 -> 2 blocks/CU. A: 64x64 bf16 LDS dbuf, XOR swizzle,
// reg-staged depth-2. B: fragment-major Wp (L2), reg-prefetched depth-1.
// Barriers are lgkm-only so prefetches stay in flight (T4); setprio on MFMA (T5).
__global__ __launch_bounds__(256) void gemm_hw(
    const float* __restrict__ H,
    const unsigned short* __restrict__ Wp,
    unsigned short* __restrict__ CZp)
{
    __shared__ unsigned char As[2 * 64 * 128];

    const int tid    = threadIdx.x;
    const int lane   = tid & 63;
    const int wave   = tid >> 6;        // 0..3
    const int wn     = wave * 64;
    const int bid    = blockIdx.x;
    const int kslice = bid & 1;
    const int m0     = (bid >> 1) * 64;

    unsigned short* CZout = CZp + (size_t)kslice * HALFCZ;

    // A staging: thread -> 16 consecutive floats of one row
    const int srow  = tid >> 2;          // 0..63
    const int scolf = (tid & 3) * 16;    // 0/16/32/48
    const float* gA = H + (size_t)(m0 + srow) * DIM + kslice * 1024 + scolf;
    const int swz   = (srow & 7) << 4;
    const int soff0 = (srow * 128 + scolf * 2) ^ swz;
    const int soff1 = (srow * 128 + scolf * 2 + 16) ^ swz;

    // B fragment base: frag index = wave*4 + j ; addr = wpb + j*32768 + s*512
    const unsigned short* wpb = Wp + (size_t)(wave * 4) * 32768 + lane * 8;

    f32x4 acc[4][4] = {};
    float4 p0[4], p1[4];
    short8 b0[2][4], b1[2][4];

#define LOADA(P, KT) { \
    _Pragma("unroll") \
    for (int q = 0; q < 4; ++q) P[q] = *(const float4*)(gA + (KT) * 64 + q * 4); }

#define LOADB(B, KT) { \
    _Pragma("unroll") \
    for (int ks = 0; ks < 2; ++ks) \
        _Pragma("unroll") \
        for (int j = 0; j < 4; ++j) \
            B[ks][j] = *(const short8*)(wpb + (size_t)j * 32768 + ((kslice << 5) + (KT) * 2 + ks) * 512); }

#define WRITES(BUFB, P) { \
    short8 lo_ = cvt8(P[0], P[1]); \
    short8 hi_ = cvt8(P[2], P[3]); \
    *(short8*)(As + (BUFB) + soff0) = lo_; \
    *(short8*)(As + (BUFB) + soff1) = hi_; }

#define COMPUTE(BUFB, B) { \
    short8 a_[2][4]; \
    _Pragma("unroll") \
    for (int ks = 0; ks < 2; ++ks) \
        _Pragma("unroll") \
        for (int i = 0; i < 4; ++i) { \
            int row_ = i * 16 + (lane & 15); \
            int off_ = (row_ * 128 + ks * 64 + ((lane >> 4) << 4)) ^ ((row_ & 7) << 4); \
            a_[ks][i] = *(const short8*)(As + (BUFB) + off_); \
        } \
    __builtin_amdgcn_s_setprio(1); \
    _Pragma("unroll") \
    for (int ks = 0; ks < 2; ++ks) \
        _Pragma("unroll") \
        for (int i = 0; i < 4; ++i) \
            _Pragma("unroll") \
            for (int j = 0; j < 4; ++j) \
                acc[i][j] = __builtin_amdgcn_mfma_f32_16x16x32_bf16(a_[ks][i], B[ks][j], acc[i][j], 0, 0, 0); \
    __builtin_amdgcn_s_setprio(0); }

    // ---- prologue: stage step0, prefetch step1 ----
    LOADA(p0, 0);
    LOADB(b0, 0);
    WRITES(0, p0);
    LOADA(p1, 1);
    BARRIER();

    // ---- 16 K-steps (K=1024), unrolled x2, 1 lgkm-barrier per step ----
    for (int it = 0; it < 16; it += 2) {
        LOADB(b1, it + 1);
        WRITES(8192, p1);                       // stage it+1 into buf1
        if (it + 2 < 16) LOADA(p0, it + 2);
        COMPUTE(0, b0);
        BARRIER();

        if (it + 2 < 16) { LOADB(b0, it + 2); WRITES(0, p0); }
        if (it + 3 < 16) LOADA(p1, it + 3);
        COMPUTE(8192, b1);
        BARRIER();
    }

    // ---- epilogue: C/D layout col=lane&15, row=(lane>>4)*4+r ; bf16 store ----
    #pragma unroll
    for (int i = 0; i < 4; ++i)
        #pragma unroll
        for (int j = 0; j < 4; ++j)
            #pragma unroll
            for (int r = 0; r < 4; ++r) {
                int row = m0 + i * 16 + (lane >> 4) * 4 + r;
                int col = wn + j * 16 + (lane & 15);
                CZout[(size_t)row * NC + col] = f2bf(acc[i][j][r]);
            }
#undef LOADA
#undef LOADB
#undef WRITES
#undef COMPUTE
}

// ---------- Kernel 3: sum split-K + gather + masked softmax + reduce ----------
__global__ __launch_bounds__(256) void finalize(
    const unsigned short* __restrict__ CZp,
    const int*   __restrict__ mask,
    const int*   __restrict__ idx,
    const float* __restrict__ Bpos,
    float*       __restrict__ out)
{
    const unsigned short* CZ0 = CZp;
    const unsigned short* CZ1 = CZp + HALFCZ;

    int t  = threadIdx.x;
    int ch = t & 127;
    int q  = blockIdx.x * 2 + (t >> 7);   // linear phrase 0..4095
    int b  = q >> 10;

    int rows[8];
    unsigned mbits = 0;
    #pragma unroll
    for (int l = 0; l < 8; ++l) {
        int m   = mask[q * 8 + l];
        int tok = idx[q * 8 + l];
        rows[l] = b * 4096 + tok;
        if (m) mbits |= 1u << l;
    }

    float z[8], c[8];
    float mx = -1e30f;
    #pragma unroll
    for (int l = 0; l < 8; ++l) {
        if (mbits & (1u << l)) {
            size_t base = (size_t)rows[l] * NC;
            z[l] = bf2f(CZ0[base + CDIM + ch]) + bf2f(CZ1[base + CDIM + ch])
                 + Bpos[l * CDIM + ch];
            c[l] = bf2f(CZ0[base + ch]) + bf2f(CZ1[base + ch]);
            mx = fmaxf(mx, z[l]);
        } else {
            z[l] = -1e30f; c[l] = 0.f;
        }
    }

    float num = 0.f, den = 0.f;
    #pragma unroll
    for (int l = 0; l < 8; ++l) {
        if (mbits & (1u << l)) {
            float w = __expf(z[l] - mx);
            den += w;
            num += w * c[l];
        }
    }
    out[(size_t)q * CDIM + ch] = mbits ? (num / den) : 0.f;
}

extern "C" void kernel_launch(void* const* d_in, const int* in_sizes, int n_in,
                              void* d_out, int out_size, void* d_ws, size_t ws_size,
                              hipStream_t stream) {
    const float* h    = (const float*)d_in[0];
    const int*   mask = (const int*)d_in[1];
    const int*   idx  = (const int*)d_in[2];
    const float* Wkv  = (const float*)d_in[3];
    const float* Wz   = (const float*)d_in[4];
    const float* Bpos = (const float*)d_in[5];
    float* out = (float*)d_out;

    unsigned short* Wp  = (unsigned short*)d_ws;                    // 1 MB packed W
    unsigned short* CZp = (unsigned short*)((char*)d_ws + 2 * 1024 * 1024); // 2x8.4 MB bf16

    convert_w<<<256, 256, 0, stream>>>(Wkv, Wz, Wp);
    gemm_hw<<<512, 256, 0, stream>>>(h, Wp, CZp);
    finalize<<<2048, 256, 0, stream>>>(CZp, mask, idx, Bpos, out);
}